// Round 11
// baseline (267.743 us; speedup 1.0000x reference)
//
#include <hip/hip_runtime.h>
#include <math.h>

#define BB_   2
#define CIN_  256
#define NTOK_ 2048
#define FF_   512
#define COUT_ 256
#define NH_   8
#define DH_   64
#define HW_   128
#define BNEPS_ 1e-5f
#define SCALE_LOG2_ 0.09016844005556021f  /* log2(e)/16, folded into K at qkv */

// Instrumentation: surface qkv/attn above the 40us harness fills in rocprof
// top-5 WITH their counter rows. Per-rep cost = dur/REP. Sacrificial round.
#define QKV_REP_  4
#define ATTN_REP_ 6

typedef __attribute__((ext_vector_type(8))) short short8;
typedef __attribute__((ext_vector_type(4))) short bfx4;
typedef __attribute__((ext_vector_type(4))) float f32x4;

#if __has_builtin(__builtin_amdgcn_mfma_f32_16x16x16_bf16)
#define MFMA16(a, b, c) __builtin_amdgcn_mfma_f32_16x16x16_bf16(a, b, c, 0, 0, 0)
#else
#define MFMA16(a, b, c) __builtin_amdgcn_mfma_f32_16x16x16bf16_1k(a, b, c, 0, 0, 0)
#endif

__device__ inline unsigned short f2bf(float f) {
  union { float f; unsigned u; } v; v.f = f;
  unsigned r = (v.u + 0x7FFF + ((v.u >> 16) & 1)) >> 16;  // RNE
  return (unsigned short)r;
}

// async global->LDS DMA, 16 B per lane; LDS dest = wave-uniform base + lane*16
__device__ __forceinline__ void dma16(const unsigned short* g, unsigned short* l) {
  __builtin_amdgcn_global_load_lds(
      (const __attribute__((address_space(1))) void*)g,
      (__attribute__((address_space(3))) void*)l, 16, 0, 0);
}

// ---------------------------------------------------------------------------
// Kernel 1 (R9 form, REP-instrumented): QKV projection, fp32 in, fused
// transpose+convert, R8 coalesced epilogue.
// ---------------------------------------------------------------------------
__global__ __launch_bounds__(256, 3) void qkv_kernel(
    const float* __restrict__ x, const float* __restrict__ WK,
    const float* __restrict__ WQ, const float* __restrict__ WV,
    unsigned short* __restrict__ Kb, unsigned short* __restrict__ Qb,
    unsigned short* __restrict__ Vt) {
  __shared__ unsigned short Wsh[128 * 72];
  __shared__ unsigned short Xsh[64 * 72];
  __shared__ float T[64 * 65];
  const int tid = threadIdx.x;
  const int lane = tid & 63, w = tid >> 6;
  const int lx = lane & 15, q = lane >> 4;
  const int wm = w >> 1, wn = w & 1;
  const int n0 = blockIdx.x * 64;
  const int f0 = blockIdx.y * 128;
  const int b = blockIdx.z / 3, which = blockIdx.z % 3;
  const float* Wb = which == 0 ? WK : which == 1 ? WQ : WV;

  const int srow = tid >> 3;          // 0..31
  const int soff = (tid & 7) * 8;     // 0..56
  const float* Wg = Wb + (size_t)(f0 + srow) * CIN_ + soff;
  const int tc = tid >> 4;            // 0..15
  const int tn = (tid & 15) * 4;

  for (int rep = 0; rep < QKV_REP_; ++rep) {
    float4 wr[4][2], xr[4];
#pragma unroll
    for (int r = 0; r < 4; ++r) {
      wr[r][0] = *(const float4*)(Wg + (size_t)(32 * r) * CIN_);
      wr[r][1] = *(const float4*)(Wg + (size_t)(32 * r) * CIN_ + 4);
    }
#pragma unroll
    for (int p = 0; p < 4; ++p)
      xr[p] = *(const float4*)(x + (size_t)(b * CIN_ + tc + 16 * p) * NTOK_ + n0 + tn);

    f32x4 acc[4][2];
#pragma unroll
    for (int i = 0; i < 4; ++i)
#pragma unroll
      for (int j = 0; j < 2; ++j) acc[i][j] = (f32x4){0.f, 0.f, 0.f, 0.f};

    for (int kk = 0; kk < 4; ++kk) {
      __syncthreads();   // (A) previous MFMA reads done; T/Wsh writable
#pragma unroll
      for (int p = 0; p < 4; ++p) {
        const int row = tc + 16 * p;
        T[row * 65 + tn + 0] = xr[p].x; T[row * 65 + tn + 1] = xr[p].y;
        T[row * 65 + tn + 2] = xr[p].z; T[row * 65 + tn + 3] = xr[p].w;
      }
#pragma unroll
      for (int r = 0; r < 4; ++r) {
        unsigned short u[8];
        u[0] = f2bf(wr[r][0].x); u[1] = f2bf(wr[r][0].y);
        u[2] = f2bf(wr[r][0].z); u[3] = f2bf(wr[r][0].w);
        u[4] = f2bf(wr[r][1].x); u[5] = f2bf(wr[r][1].y);
        u[6] = f2bf(wr[r][1].z); u[7] = f2bf(wr[r][1].w);
        *(uint4*)(Wsh + (srow + 32 * r) * 72 + soff) = *(uint4*)u;
      }
      __syncthreads();   // (B) T ready
#pragma unroll
      for (int p = 0; p < 2; ++p) {
        const int idx = tid + 256 * p;
        const int nl = idx >> 3, c8 = (idx & 7) * 8;
        unsigned short u[8];
#pragma unroll
        for (int i = 0; i < 8; ++i) u[i] = f2bf(T[(c8 + i) * 65 + nl]);
        *(uint4*)(Xsh + nl * 72 + c8) = *(uint4*)u;
      }
      if (kk < 3) {
        const int c0 = (kk + 1) * 64;
#pragma unroll
        for (int r = 0; r < 4; ++r) {
          wr[r][0] = *(const float4*)(Wg + (size_t)(32 * r) * CIN_ + c0);
          wr[r][1] = *(const float4*)(Wg + (size_t)(32 * r) * CIN_ + c0 + 4);
        }
#pragma unroll
        for (int p = 0; p < 4; ++p)
          xr[p] = *(const float4*)(x + (size_t)(b * CIN_ + c0 + tc + 16 * p) * NTOK_ + n0 + tn);
      }
      __syncthreads();   // (C) Xsh/Wsh ready
      short8 xF[2][2];
#pragma unroll
      for (int i = 0; i < 2; ++i) {
        xF[i][0] = *(const short8*)(Xsh + (32 * wn + 16 * i + lx) * 72 + q * 8);
        xF[i][1] = *(const short8*)(Xsh + (32 * wn + 16 * i + lx) * 72 + 32 + q * 8);
      }
      if (which < 2) {
#pragma unroll
        for (int i = 0; i < 4; ++i) {
          const short8 w0 = *(const short8*)(Wsh + (64 * wm + 16 * i + lx) * 72 + q * 8);
          const short8 w1 = *(const short8*)(Wsh + (64 * wm + 16 * i + lx) * 72 + 32 + q * 8);
#pragma unroll
          for (int j = 0; j < 2; ++j) {
            acc[i][j] = __builtin_amdgcn_mfma_f32_16x16x32_bf16(w0, xF[j][0], acc[i][j], 0, 0, 0);
            acc[i][j] = __builtin_amdgcn_mfma_f32_16x16x32_bf16(w1, xF[j][1], acc[i][j], 0, 0, 0);
          }
        }
      } else {
#pragma unroll
        for (int jf = 0; jf < 4; ++jf) {
          const short8 w0 = *(const short8*)(Wsh + (64 * wm + 16 * jf + lx) * 72 + q * 8);
          const short8 w1 = *(const short8*)(Wsh + (64 * wm + 16 * jf + lx) * 72 + 32 + q * 8);
#pragma unroll
          for (int i = 0; i < 2; ++i) {
            acc[jf][i] = __builtin_amdgcn_mfma_f32_16x16x32_bf16(xF[i][0], w0, acc[jf][i], 0, 0, 0);
            acc[jf][i] = __builtin_amdgcn_mfma_f32_16x16x32_bf16(xF[i][1], w1, acc[jf][i], 0, 0, 0);
          }
        }
      }
    }

    // ---- coalesced epilogue (R8)
    __syncthreads();

    if (which < 2) {
      const float sc = (which == 0) ? SCALE_LOG2_ : 1.0f;
#pragma unroll
      for (int i = 0; i < 4; ++i)
#pragma unroll
        for (int j = 0; j < 2; ++j) {
          const int row = wm * 64 + 32 * wn + 16 * j + lx;
          const int d0 = 16 * i + 4 * q;
          ushort4 u;
          u.x = f2bf(acc[i][j][0] * sc); u.y = f2bf(acc[i][j][1] * sc);
          u.z = f2bf(acc[i][j][2] * sc); u.w = f2bf(acc[i][j][3] * sc);
          *(ushort4*)(Wsh + row * 72 + d0) = u;
        }
    } else {
#pragma unroll
      for (int jf = 0; jf < 4; ++jf)
#pragma unroll
        for (int i = 0; i < 2; ++i) {
          const int row = wm * 64 + 16 * jf + lx;
          const int nc = 32 * wn + 16 * i + 4 * q;
          ushort4 u;
          u.x = f2bf(acc[jf][i][0]); u.y = f2bf(acc[jf][i][1]);
          u.z = f2bf(acc[jf][i][2]); u.w = f2bf(acc[jf][i][3]);
          *(ushort4*)(Wsh + row * 72 + nc) = u;
        }
    }
    __syncthreads();

    const int h0 = f0 >> 6;
    if (which < 2) {
      unsigned short* Y = (which == 0 ? Kb : Qb);
#pragma unroll
      for (int p = 0; p < 4; ++p) {
        const int idx = tid + 256 * p;
        const int row = idx >> 3;
        const int c = (idx & 7) * 8;
        const uint4 val = *(const uint4*)(Wsh + row * 72 + c);
        *(uint4*)(Y + ((size_t)((b * NH_ + h0 + (row >> 6)) * NTOK_ + n0 + (row & 63))) * DH_ + c) = val;
      }
    } else {
#pragma unroll
      for (int p = 0; p < 4; ++p) {
        const int idx = tid + 256 * p;
        const int row = idx >> 3;
        const int c = (idx & 7) * 8;
        const uint4 val = *(const uint4*)(Wsh + row * 72 + c);
        *(uint4*)(Vt + ((size_t)((b * NH_ + h0 + (row >> 6)) * DH_ + (row & 63))) * NTOK_ + n0 + c) = val;
      }
    }
    asm volatile("" ::: "memory");   // block cross-rep DSE/CSE
  }
}

// ---------------------------------------------------------------------------
// Kernel 2 (R9 form, REP-instrumented): block-causal attention.
// ---------------------------------------------------------------------------
__global__ __launch_bounds__(256, 2) void attn_kernel(
    const unsigned short* __restrict__ Kb, const unsigned short* __restrict__ Qb,
    const unsigned short* __restrict__ Vt, unsigned short* __restrict__ Ob) {
  __shared__ __align__(16) unsigned short Qbuf[2][8192];
  __shared__ __align__(16) unsigned short Vbuf[2][8192];

  const int tid = threadIdx.x;
  const int lane = tid & 63;
  const int w = tid >> 6;
  const int lx = lane & 15;
  const int g = lane >> 4;

  const int bid = blockIdx.x;
  const int xcd = bid & 7;
  const int k = bid >> 3;
  const int bh = xcd * 2 + (k & 1);
  const int u = k >> 1;
  const int iblk = (u < 16) ? (31 - u) : (u - 16);
  const int h = bh & 7, b = bh >> 3;
  const int i0 = iblk * 64;
  const int njt = (iblk >> 1) + 1;

  const size_t bhs = (size_t)b * NH_ + h;
  const unsigned short* Kg = Kb + bhs * (size_t)NTOK_ * DH_ + (size_t)i0 * DH_;
  const unsigned short* Qg = Qb + bhs * (size_t)NTOK_ * DH_;
  const unsigned short* Vg = Vt + bhs * (size_t)DH_ * NTOK_;

  auto stage = [&](int buf, int j0) {
#pragma unroll
    for (int cc = 0; cc < 4; ++cc) {
      const int chunk = 4 * w + cc;
      {  // Q
        const int row = chunk * 8 + (lane >> 3);
        const int grp = (lane & 7) ^ (row & 7);
        dma16(Qg + (size_t)(j0 + row) * DH_ + grp * 8, &Qbuf[buf][chunk * 512]);
      }
      {  // V
        const int row = chunk * 4 + (lane >> 4);
        const int grp = (lane & 15) ^ (row & 7);
        dma16(Vg + (size_t)row * NTOK_ + j0 + grp * 8, &Vbuf[buf][chunk * 512]);
      }
    }
  };

  const int fr0 = ((g ^ (lx & 7)) << 3);
  const int fr1 = (((4 + g) ^ (lx & 7)) << 3);

  for (int rep = 0; rep < ATTN_REP_; ++rep) {
    const short8 aK0 = *(const short8*)(Kg + (16 * w + lx) * DH_ + g * 8);
    const short8 aK1 = *(const short8*)(Kg + (16 * w + lx) * DH_ + 32 + g * 8);

    f32x4 o[4];
#pragma unroll
    for (int t = 0; t < 4; ++t) o[t] = (f32x4){0.f, 0.f, 0.f, 0.f};
    float rs = 0.f;

    stage(0, 0);
    __syncthreads();

    int cur = 0;
    for (int jt = 0; jt < njt; ++jt) {
      if (jt + 1 < njt) stage(cur ^ 1, (jt + 1) * 128);

      const unsigned short* Qs = Qbuf[cur];
      const unsigned short* Vs = Vbuf[cur];

      f32x4 sa[8];
#pragma unroll
      for (int s = 0; s < 8; ++s) {
        const int row = 16 * s + lx;
        const short8 a0 = *(const short8*)(Qs + row * 64 + fr0);
        const short8 a1 = *(const short8*)(Qs + row * 64 + fr1);
        sa[s] = (f32x4){0.f, 0.f, 0.f, 0.f};
        sa[s] = __builtin_amdgcn_mfma_f32_16x16x32_bf16(a0, aK0, sa[s], 0, 0, 0);
        sa[s] = __builtin_amdgcn_mfma_f32_16x16x32_bf16(a1, aK1, sa[s], 0, 0, 0);
      }

#pragma unroll
      for (int s = 0; s < 8; ++s) {
        const float p0 = __builtin_amdgcn_exp2f(sa[s][0]);
        const float p1 = __builtin_amdgcn_exp2f(sa[s][1]);
        const float p2 = __builtin_amdgcn_exp2f(sa[s][2]);
        const float p3 = __builtin_amdgcn_exp2f(sa[s][3]);
        rs += (p0 + p1) + (p2 + p3);
        union { unsigned u[2]; bfx4 v; } pk;
        pk.u[0] = (__builtin_bit_cast(unsigned, p0) >> 16) |
                  (__builtin_bit_cast(unsigned, p1) & 0xFFFF0000u);
        pk.u[1] = (__builtin_bit_cast(unsigned, p2) >> 16) |
                  (__builtin_bit_cast(unsigned, p3) & 0xFFFF0000u);
        const int jgrp = 2 * s + (g >> 1);
        const int joff = (g & 1) << 2;
#pragma unroll
        for (int t = 0; t < 4; ++t) {
          const int row = 16 * t + lx;
          const bfx4 va = *(const bfx4*)(Vs + row * 128 +
                                         ((jgrp ^ (row & 7)) << 3) + joff);
          o[t] = MFMA16(va, pk.v, o[t]);
        }
      }

      __syncthreads();
      cur ^= 1;
    }

    rs += __shfl_xor(rs, 16);
    rs += __shfl_xor(rs, 32);
    const float invl = 1.0f / rs;
    const int n = i0 + 16 * w + lx;
#pragma unroll
    for (int t = 0; t < 4; ++t) {
      ushort4 uo;
      uo.x = f2bf(o[t][0] * invl); uo.y = f2bf(o[t][1] * invl);
      uo.z = f2bf(o[t][2] * invl); uo.w = f2bf(o[t][3] * invl);
      *(ushort4*)(Ob + ((size_t)(b * NTOK_ + n)) * FF_ + h * 64 + 16 * t + 4 * g) = uo;
    }
    __syncthreads();                 // guard Qbuf[0] rewrite next rep
    asm volatile("" ::: "memory");
  }
}

// ---------------------------------------------------------------------------
// Kernel 3: output projection + bias + ReLU + skip -> d_out fp32 (R9 form).
// ---------------------------------------------------------------------------
__global__ __launch_bounds__(256, 2) void proj_kernel(
    const unsigned short* __restrict__ Ob, const float* __restrict__ Wo,
    const float* __restrict__ bo, const float* __restrict__ x,
    float* __restrict__ pre) {
  __shared__ unsigned short Osh[32 * 72];
  __shared__ unsigned short Wsh[64 * 72];
  const int tid = threadIdx.x;
  const int lane = tid & 63, w = tid >> 6;
  const int lx = lane & 15, q = lane >> 4;
  const int n0 = blockIdx.x * 32;
  const int o0 = blockIdx.y * 64;
  const int b = blockIdx.z;

  const int srow = tid >> 3;
  const int soff = (tid & 7) * 8;
  const unsigned short* Og = Ob + ((size_t)(b * NTOK_ + n0 + srow)) * FF_ + soff;
  const float* Wg = Wo + (size_t)(o0 + srow) * FF_ + soff;

  uint4 orr;
  float4 wrr[2][2];
  orr = *(const uint4*)(Og);
#pragma unroll
  for (int r = 0; r < 2; ++r) {
    wrr[r][0] = *(const float4*)(Wg + (size_t)(32 * r) * FF_);
    wrr[r][1] = *(const float4*)(Wg + (size_t)(32 * r) * FF_ + 4);
  }

  f32x4 acc[2];
#pragma unroll
  for (int i = 0; i < 2; ++i) acc[i] = (f32x4){0.f, 0.f, 0.f, 0.f};

  for (int kk = 0; kk < 8; ++kk) {
    __syncthreads();
    *(uint4*)(Osh + srow * 72 + soff) = orr;
#pragma unroll
    for (int r = 0; r < 2; ++r) {
      unsigned short u[8];
      u[0] = f2bf(wrr[r][0].x); u[1] = f2bf(wrr[r][0].y);
      u[2] = f2bf(wrr[r][0].z); u[3] = f2bf(wrr[r][0].w);
      u[4] = f2bf(wrr[r][1].x); u[5] = f2bf(wrr[r][1].y);
      u[6] = f2bf(wrr[r][1].z); u[7] = f2bf(wrr[r][1].w);
      *(uint4*)(Wsh + (srow + 32 * r) * 72 + soff) = *(uint4*)u;
    }
    if (kk < 7) {
      const int c0 = (kk + 1) * 64;
      orr = *(const uint4*)(Og + c0);
#pragma unroll
      for (int r = 0; r < 2; ++r) {
        wrr[r][0] = *(const float4*)(Wg + (size_t)(32 * r) * FF_ + c0);
        wrr[r][1] = *(const float4*)(Wg + (size_t)(32 * r) * FF_ + c0 + 4);
      }
    }
    __syncthreads();
    short8 aF[2][2], bF[2];
#pragma unroll
    for (int i = 0; i < 2; ++i) {
      aF[i][0] = *(const short8*)(Osh + (16 * i + lx) * 72 + q * 8);
      aF[i][1] = *(const short8*)(Osh + (16 * i + lx) * 72 + 32 + q * 8);
    }
    bF[0] = *(const short8*)(Wsh + (16 * w + lx) * 72 + q * 8);
    bF[1] = *(const short8*)(Wsh + (16 * w + lx) * 72 + 32 + q * 8);
#pragma unroll
    for (int i = 0; i < 2; ++i) {
      acc[i] = __builtin_amdgcn_mfma_f32_16x16x32_bf16(aF[i][0], bF[0], acc[i], 0, 0, 0);
      acc[i] = __builtin_amdgcn_mfma_f32_16x16x32_bf16(aF[i][1], bF[1], acc[i], 0, 0, 0);
    }
  }

  const int o = o0 + 16 * w + lx;
  const float bias = bo[o];
#pragma unroll
  for (int i = 0; i < 2; ++i) {
    const int n = n0 + 16 * i + 4 * q;
    const float4 xv = *(const float4*)(x + ((size_t)(b * CIN_ + o)) * NTOK_ + n);
    float4 v;
    v.x = fmaxf(acc[i][0] + bias, 0.f) + xv.x;
    v.y = fmaxf(acc[i][1] + bias, 0.f) + xv.y;
    v.z = fmaxf(acc[i][2] + bias, 0.f) + xv.z;
    v.w = fmaxf(acc[i][3] + bias, 0.f) + xv.w;
    *(float4*)(pre + ((size_t)(b * COUT_ + o)) * NTOK_ + n) = v;
  }
}

// ---------------------------------------------------------------------------
// Kernel 4: BatchNorm in place, 512 threads/block (R9 form).
// ---------------------------------------------------------------------------
__global__ __launch_bounds__(512) void bn_kernel(
    float* __restrict__ out, const float* __restrict__ gamma,
    const float* __restrict__ beta) {
  __shared__ float red[16];
  const int c = blockIdx.x;
  const int tid = threadIdx.x;
  const int lane = tid & 63, w = tid >> 6;

  float4 v[2];
  float s = 0.f, s2 = 0.f;
#pragma unroll
  for (int b = 0; b < BB_; ++b) {
    float* base = out + ((size_t)(b * COUT_ + c)) * NTOK_;
    const float4 t = *(const float4*)(base + 4 * tid);
    v[b] = t;
    s += t.x + t.y + t.z + t.w;
    s2 += t.x * t.x + t.y * t.y + t.z * t.z + t.w * t.w;
  }
#pragma unroll
  for (int off = 32; off >= 1; off >>= 1) {
    s += __shfl_xor(s, off);
    s2 += __shfl_xor(s2, off);
  }
  if (lane == 0) { red[w] = s; red[8 + w] = s2; }
  __syncthreads();
  float S = 0.f, S2 = 0.f;
#pragma unroll
  for (int i = 0; i < 8; ++i) { S += red[i]; S2 += red[8 + i]; }
  const float inv = 1.0f / (float)(BB_ * NTOK_);
  const float mean = S * inv;
  const float var = S2 * inv - mean * mean;
  const float sc = rsqrtf(var + BNEPS_) * gamma[c];
  const float bt = beta[c];
#pragma unroll
  for (int b = 0; b < BB_; ++b) {
    float* base = out + ((size_t)(b * COUT_ + c)) * NTOK_;
    float4 t = v[b];
    t.x = (t.x - mean) * sc + bt;
    t.y = (t.y - mean) * sc + bt;
    t.z = (t.z - mean) * sc + bt;
    t.w = (t.w - mean) * sc + bt;
    *(float4*)(base + 4 * tid) = t;
  }
}

extern "C" void kernel_launch(void* const* d_in, const int* in_sizes, int n_in,
                              void* d_out, int out_size, void* d_ws, size_t ws_size,
                              hipStream_t stream) {
  (void)in_sizes; (void)n_in; (void)out_size; (void)ws_size;
  const float* x = (const float*)d_in[0];
  const float* WK = (const float*)d_in[1];
  const float* WQ = (const float*)d_in[2];
  const float* WV = (const float*)d_in[3];
  const float* Wo = (const float*)d_in[4];
  const float* bo = (const float*)d_in[5];
  const float* gamma = (const float*)d_in[6];
  const float* beta = (const float*)d_in[7];

  char* ws = (char*)d_ws;
  unsigned short* Kb  = (unsigned short*)(ws + 3145728);          // 4 MB
  unsigned short* Qb  = (unsigned short*)(ws + 7340032);          // 4 MB
  unsigned short* Vt  = (unsigned short*)(ws + 11534336);         // 4 MB
  unsigned short* Ob  = (unsigned short*)(ws + 15728640);         // 4 MB
  float* out = (float*)d_out;

  qkv_kernel<<<dim3(32, 4, 6), 256, 0, stream>>>(x, WK, WQ, WV, Kb, Qb, Vt);
  attn_kernel<<<dim3(512, 1, 1), 256, 0, stream>>>(Kb, Qb, Vt, Ob);
  proj_kernel<<<dim3(64, 4, 2), 256, 0, stream>>>(Ob, Wo, bo, x, out);
  bn_kernel<<<256, 512, 0, stream>>>(out, gamma, beta);
}

// Round 12
// 193.220 us; speedup vs baseline: 1.3857x; 1.3857x over previous
//
#include <hip/hip_runtime.h>
#include <math.h>

#define BB_   2
#define CIN_  256
#define NTOK_ 2048
#define FF_   512
#define COUT_ 256
#define NH_   8
#define DH_   64
#define HW_   128
#define BNEPS_ 1e-5f
#define SCALE_LOG2_ 0.09016844005556021f  /* log2(e)/16, folded into K at qkv */

typedef __attribute__((ext_vector_type(8))) short short8;
typedef __attribute__((ext_vector_type(4))) short bfx4;
typedef __attribute__((ext_vector_type(4))) float f32x4;

#if __has_builtin(__builtin_amdgcn_mfma_f32_16x16x16_bf16)
#define MFMA16(a, b, c) __builtin_amdgcn_mfma_f32_16x16x16_bf16(a, b, c, 0, 0, 0)
#else
#define MFMA16(a, b, c) __builtin_amdgcn_mfma_f32_16x16x16bf16_1k(a, b, c, 0, 0, 0)
#endif

__device__ inline unsigned short f2bf(float f) {
  union { float f; unsigned u; } v; v.f = f;
  unsigned r = (v.u + 0x7FFF + ((v.u >> 16) & 1)) >> 16;  // RNE
  return (unsigned short)r;
}

// ---------------------------------------------------------------------------
// Kernel 1 (R9 form): QKV projection reading x/W fp32 directly; in-kernel
// transpose+bf16 convert (bit-identical to old prep); R8 coalesced epilogue.
// ---------------------------------------------------------------------------
__global__ __launch_bounds__(256, 3) void qkv_kernel(
    const float* __restrict__ x, const float* __restrict__ WK,
    const float* __restrict__ WQ, const float* __restrict__ WV,
    unsigned short* __restrict__ Kb, unsigned short* __restrict__ Qb,
    unsigned short* __restrict__ Vt) {
  __shared__ unsigned short Wsh[128 * 72];
  __shared__ unsigned short Xsh[64 * 72];
  __shared__ float T[64 * 65];
  const int tid = threadIdx.x;
  const int lane = tid & 63, w = tid >> 6;
  const int lx = lane & 15, q = lane >> 4;
  const int wm = w >> 1, wn = w & 1;
  const int n0 = blockIdx.x * 64;
  const int f0 = blockIdx.y * 128;
  const int b = blockIdx.z / 3, which = blockIdx.z % 3;
  const float* Wb = which == 0 ? WK : which == 1 ? WQ : WV;

  const int srow = tid >> 3;          // 0..31
  const int soff = (tid & 7) * 8;     // 0..56
  const float* Wg = Wb + (size_t)(f0 + srow) * CIN_ + soff;
  const int tc = tid >> 4;            // 0..15
  const int tn = (tid & 15) * 4;

  float4 wr[4][2], xr[4];
#pragma unroll
  for (int r = 0; r < 4; ++r) {
    wr[r][0] = *(const float4*)(Wg + (size_t)(32 * r) * CIN_);
    wr[r][1] = *(const float4*)(Wg + (size_t)(32 * r) * CIN_ + 4);
  }
#pragma unroll
  for (int p = 0; p < 4; ++p)
    xr[p] = *(const float4*)(x + (size_t)(b * CIN_ + tc + 16 * p) * NTOK_ + n0 + tn);

  f32x4 acc[4][2];
#pragma unroll
  for (int i = 0; i < 4; ++i)
#pragma unroll
    for (int j = 0; j < 2; ++j) acc[i][j] = (f32x4){0.f, 0.f, 0.f, 0.f};

  for (int kk = 0; kk < 4; ++kk) {
    __syncthreads();   // (A) previous MFMA reads done; T/Wsh writable
#pragma unroll
    for (int p = 0; p < 4; ++p) {
      const int row = tc + 16 * p;
      T[row * 65 + tn + 0] = xr[p].x; T[row * 65 + tn + 1] = xr[p].y;
      T[row * 65 + tn + 2] = xr[p].z; T[row * 65 + tn + 3] = xr[p].w;
    }
#pragma unroll
    for (int r = 0; r < 4; ++r) {
      unsigned short u[8];
      u[0] = f2bf(wr[r][0].x); u[1] = f2bf(wr[r][0].y);
      u[2] = f2bf(wr[r][0].z); u[3] = f2bf(wr[r][0].w);
      u[4] = f2bf(wr[r][1].x); u[5] = f2bf(wr[r][1].y);
      u[6] = f2bf(wr[r][1].z); u[7] = f2bf(wr[r][1].w);
      *(uint4*)(Wsh + (srow + 32 * r) * 72 + soff) = *(uint4*)u;
    }
    __syncthreads();   // (B) T ready
#pragma unroll
    for (int p = 0; p < 2; ++p) {
      const int idx = tid + 256 * p;
      const int nl = idx >> 3, c8 = (idx & 7) * 8;
      unsigned short u[8];
#pragma unroll
      for (int i = 0; i < 8; ++i) u[i] = f2bf(T[(c8 + i) * 65 + nl]);
      *(uint4*)(Xsh + nl * 72 + c8) = *(uint4*)u;
    }
    if (kk < 3) {
      const int c0 = (kk + 1) * 64;
#pragma unroll
      for (int r = 0; r < 4; ++r) {
        wr[r][0] = *(const float4*)(Wg + (size_t)(32 * r) * CIN_ + c0);
        wr[r][1] = *(const float4*)(Wg + (size_t)(32 * r) * CIN_ + c0 + 4);
      }
#pragma unroll
      for (int p = 0; p < 4; ++p)
        xr[p] = *(const float4*)(x + (size_t)(b * CIN_ + c0 + tc + 16 * p) * NTOK_ + n0 + tn);
    }
    __syncthreads();   // (C) Xsh/Wsh ready
    short8 xF[2][2];
#pragma unroll
    for (int i = 0; i < 2; ++i) {
      xF[i][0] = *(const short8*)(Xsh + (32 * wn + 16 * i + lx) * 72 + q * 8);
      xF[i][1] = *(const short8*)(Xsh + (32 * wn + 16 * i + lx) * 72 + 32 + q * 8);
    }
    if (which < 2) {
#pragma unroll
      for (int i = 0; i < 4; ++i) {
        const short8 w0 = *(const short8*)(Wsh + (64 * wm + 16 * i + lx) * 72 + q * 8);
        const short8 w1 = *(const short8*)(Wsh + (64 * wm + 16 * i + lx) * 72 + 32 + q * 8);
#pragma unroll
        for (int j = 0; j < 2; ++j) {
          acc[i][j] = __builtin_amdgcn_mfma_f32_16x16x32_bf16(w0, xF[j][0], acc[i][j], 0, 0, 0);
          acc[i][j] = __builtin_amdgcn_mfma_f32_16x16x32_bf16(w1, xF[j][1], acc[i][j], 0, 0, 0);
        }
      }
    } else {
#pragma unroll
      for (int jf = 0; jf < 4; ++jf) {
        const short8 w0 = *(const short8*)(Wsh + (64 * wm + 16 * jf + lx) * 72 + q * 8);
        const short8 w1 = *(const short8*)(Wsh + (64 * wm + 16 * jf + lx) * 72 + 32 + q * 8);
#pragma unroll
        for (int i = 0; i < 2; ++i) {
          acc[jf][i] = __builtin_amdgcn_mfma_f32_16x16x32_bf16(xF[i][0], w0, acc[jf][i], 0, 0, 0);
          acc[jf][i] = __builtin_amdgcn_mfma_f32_16x16x32_bf16(xF[i][1], w1, acc[jf][i], 0, 0, 0);
        }
      }
    }
  }

  // ---- coalesced epilogue (R8)
  __syncthreads();

  if (which < 2) {
    const float sc = (which == 0) ? SCALE_LOG2_ : 1.0f;
#pragma unroll
    for (int i = 0; i < 4; ++i)
#pragma unroll
      for (int j = 0; j < 2; ++j) {
        const int row = wm * 64 + 32 * wn + 16 * j + lx;
        const int d0 = 16 * i + 4 * q;
        ushort4 u;
        u.x = f2bf(acc[i][j][0] * sc); u.y = f2bf(acc[i][j][1] * sc);
        u.z = f2bf(acc[i][j][2] * sc); u.w = f2bf(acc[i][j][3] * sc);
        *(ushort4*)(Wsh + row * 72 + d0) = u;
      }
  } else {
#pragma unroll
    for (int jf = 0; jf < 4; ++jf)
#pragma unroll
      for (int i = 0; i < 2; ++i) {
        const int row = wm * 64 + 16 * jf + lx;
        const int nc = 32 * wn + 16 * i + 4 * q;
        ushort4 u;
        u.x = f2bf(acc[jf][i][0]); u.y = f2bf(acc[jf][i][1]);
        u.z = f2bf(acc[jf][i][2]); u.w = f2bf(acc[jf][i][3]);
        *(ushort4*)(Wsh + row * 72 + nc) = u;
      }
  }
  __syncthreads();

  const int h0 = f0 >> 6;
  if (which < 2) {
    unsigned short* Y = (which == 0 ? Kb : Qb);
#pragma unroll
    for (int p = 0; p < 4; ++p) {
      const int idx = tid + 256 * p;
      const int row = idx >> 3;
      const int c = (idx & 7) * 8;
      const uint4 val = *(const uint4*)(Wsh + row * 72 + c);
      *(uint4*)(Y + ((size_t)((b * NH_ + h0 + (row >> 6)) * NTOK_ + n0 + (row & 63))) * DH_ + c) = val;
    }
  } else {
#pragma unroll
    for (int p = 0; p < 4; ++p) {
      const int idx = tid + 256 * p;
      const int row = idx >> 3;
      const int c = (idx & 7) * 8;
      const uint4 val = *(const uint4*)(Wsh + row * 72 + c);
      *(uint4*)(Vt + ((size_t)((b * NH_ + h0 + (row >> 6)) * DH_ + (row & 63))) * NTOK_ + n0 + c) = val;
    }
  }
}

// ---------------------------------------------------------------------------
// Kernel 2 (R12): block-causal attention, NO LDS. R11 counters: MfmaUtil 25%,
// VALUBusy 31%, hbm 79 GB/s, 2.2M conflict-cyc/rep -> latency-bound on the
// per-tile DMA-drain barrier + LDS conflicts, while all K/Q/V (512 KB per bh)
// is L2/L3-resident. Fix per Common-mistake #7: drop staging; read Q/V
// fragments straight from global with de-swizzled addresses (verified equal
// to the staged values: a0=Q[j0+row][g*8], a1=Q[j0+row][32+g*8],
// va=V[16t+lx][j0+16s+4g]). Zero barriers; waves fully independent;
// bit-identical math.
// ---------------------------------------------------------------------------
__global__ __launch_bounds__(256) void attn_kernel(
    const unsigned short* __restrict__ Kb, const unsigned short* __restrict__ Qb,
    const unsigned short* __restrict__ Vt, unsigned short* __restrict__ Ob) {
  const int tid = threadIdx.x;
  const int lane = tid & 63;
  const int w = tid >> 6;
  const int lx = lane & 15;
  const int g = lane >> 4;

  const int bid = blockIdx.x;
  const int xcd = bid & 7;
  const int k = bid >> 3;
  const int bh = xcd * 2 + (k & 1);
  const int u = k >> 1;
  const int iblk = (u < 16) ? (31 - u) : (u - 16);   // LPT heavy-first
  const int h = bh & 7, b = bh >> 3;
  const int i0 = iblk * 64;
  const int njt = (iblk >> 1) + 1;   // 128-wide j-tiles; 1..16

  const size_t bhs = (size_t)b * NH_ + h;
  const unsigned short* Kg = Kb + bhs * (size_t)NTOK_ * DH_ + (size_t)i0 * DH_;
  const unsigned short* Qg = Qb + bhs * (size_t)NTOK_ * DH_;
  const unsigned short* Vg = Vt + bhs * (size_t)DH_ * NTOK_;

  // K B-frags (one-time): B[k=d=8g+e][n=i=lx]
  const short8 aK0 = *(const short8*)(Kg + (16 * w + lx) * DH_ + g * 8);
  const short8 aK1 = *(const short8*)(Kg + (16 * w + lx) * DH_ + 32 + g * 8);

  f32x4 o[4];      // O^T accum: row d=16t+4g+r, col i=lx (token i0+16w+lx)
#pragma unroll
  for (int t = 0; t < 4; ++t) o[t] = (f32x4){0.f, 0.f, 0.f, 0.f};
  float rs = 0.f;  // per-lane row sum for i = 16w+lx

  // V row bases for the 4 t-rows this lane reads (d = 16t+lx)
  const unsigned short* Vrow0 = Vg + (size_t)(lx) * NTOK_;
  const unsigned short* Vrow1 = Vg + (size_t)(16 + lx) * NTOK_;
  const unsigned short* Vrow2 = Vg + (size_t)(32 + lx) * NTOK_;
  const unsigned short* Vrow3 = Vg + (size_t)(48 + lx) * NTOK_;

  for (int jt = 0; jt < njt; ++jt) {
    const int j0 = jt * 128;

    // S^T phase: sa[s] = S^T[j=16s+4g+r][i=lx], A=Q rows j (direct global)
    f32x4 sa[8];
#pragma unroll
    for (int s = 0; s < 8; ++s) {
      const int row = j0 + 16 * s + lx;
      const short8 a0 = *(const short8*)(Qg + (size_t)row * DH_ + g * 8);
      const short8 a1 = *(const short8*)(Qg + (size_t)row * DH_ + 32 + g * 8);
      sa[s] = (f32x4){0.f, 0.f, 0.f, 0.f};
      sa[s] = __builtin_amdgcn_mfma_f32_16x16x32_bf16(a0, aK0, sa[s], 0, 0, 0);
      sa[s] = __builtin_amdgcn_mfma_f32_16x16x32_bf16(a1, aK1, sa[s], 0, 0, 0);
    }

    // exp2 -> packed P (B operand), PV via 16x16x16 MFMAs, V direct global
#pragma unroll
    for (int s = 0; s < 8; ++s) {
      const float p0 = __builtin_amdgcn_exp2f(sa[s][0]);
      const float p1 = __builtin_amdgcn_exp2f(sa[s][1]);
      const float p2 = __builtin_amdgcn_exp2f(sa[s][2]);
      const float p3 = __builtin_amdgcn_exp2f(sa[s][3]);
      rs += (p0 + p1) + (p2 + p3);
      union { unsigned u[2]; bfx4 v; } pk;
      pk.u[0] = (__builtin_bit_cast(unsigned, p0) >> 16) |
                (__builtin_bit_cast(unsigned, p1) & 0xFFFF0000u);
      pk.u[1] = (__builtin_bit_cast(unsigned, p2) >> 16) |
                (__builtin_bit_cast(unsigned, p3) & 0xFFFF0000u);
      const int jc = j0 + 16 * s + 4 * g;   // A[m=d=16t+lx][k=j=16s+4g+e]
      const bfx4 va0 = *(const bfx4*)(Vrow0 + jc);
      const bfx4 va1 = *(const bfx4*)(Vrow1 + jc);
      const bfx4 va2 = *(const bfx4*)(Vrow2 + jc);
      const bfx4 va3 = *(const bfx4*)(Vrow3 + jc);
      o[0] = MFMA16(va0, pk.v, o[0]);
      o[1] = MFMA16(va1, pk.v, o[1]);
      o[2] = MFMA16(va2, pk.v, o[2]);
      o[3] = MFMA16(va3, pk.v, o[3]);
    }
  }

  // reduce per-lane row sums across the 4 g-groups (same i = 16w+lx)
  rs += __shfl_xor(rs, 16);
  rs += __shfl_xor(rs, 32);
  const float invl = 1.0f / rs;
  const int n = i0 + 16 * w + lx;
#pragma unroll
  for (int t = 0; t < 4; ++t) {
    ushort4 uo;
    uo.x = f2bf(o[t][0] * invl); uo.y = f2bf(o[t][1] * invl);
    uo.z = f2bf(o[t][2] * invl); uo.w = f2bf(o[t][3] * invl);
    *(ushort4*)(Ob + ((size_t)(b * NTOK_ + n)) * FF_ + h * 64 + 16 * t + 4 * g) = uo;
  }
}

// ---------------------------------------------------------------------------
// Kernel 3: output projection + bias + ReLU + skip -> d_out fp32 (R9 form).
// ---------------------------------------------------------------------------
__global__ __launch_bounds__(256, 2) void proj_kernel(
    const unsigned short* __restrict__ Ob, const float* __restrict__ Wo,
    const float* __restrict__ bo, const float* __restrict__ x,
    float* __restrict__ pre) {
  __shared__ unsigned short Osh[32 * 72];
  __shared__ unsigned short Wsh[64 * 72];
  const int tid = threadIdx.x;
  const int lane = tid & 63, w = tid >> 6;
  const int lx = lane & 15, q = lane >> 4;
  const int n0 = blockIdx.x * 32;
  const int o0 = blockIdx.y * 64;
  const int b = blockIdx.z;

  const int srow = tid >> 3;
  const int soff = (tid & 7) * 8;
  const unsigned short* Og = Ob + ((size_t)(b * NTOK_ + n0 + srow)) * FF_ + soff;
  const float* Wg = Wo + (size_t)(o0 + srow) * FF_ + soff;

  uint4 orr;
  float4 wrr[2][2];
  orr = *(const uint4*)(Og);
#pragma unroll
  for (int r = 0; r < 2; ++r) {
    wrr[r][0] = *(const float4*)(Wg + (size_t)(32 * r) * FF_);
    wrr[r][1] = *(const float4*)(Wg + (size_t)(32 * r) * FF_ + 4);
  }

  f32x4 acc[2];
#pragma unroll
  for (int i = 0; i < 2; ++i) acc[i] = (f32x4){0.f, 0.f, 0.f, 0.f};

  for (int kk = 0; kk < 8; ++kk) {
    __syncthreads();
    *(uint4*)(Osh + srow * 72 + soff) = orr;
#pragma unroll
    for (int r = 0; r < 2; ++r) {
      unsigned short u[8];
      u[0] = f2bf(wrr[r][0].x); u[1] = f2bf(wrr[r][0].y);
      u[2] = f2bf(wrr[r][0].z); u[3] = f2bf(wrr[r][0].w);
      u[4] = f2bf(wrr[r][1].x); u[5] = f2bf(wrr[r][1].y);
      u[6] = f2bf(wrr[r][1].z); u[7] = f2bf(wrr[r][1].w);
      *(uint4*)(Wsh + (srow + 32 * r) * 72 + soff) = *(uint4*)u;
    }
    if (kk < 7) {
      const int c0 = (kk + 1) * 64;
      orr = *(const uint4*)(Og + c0);
#pragma unroll
      for (int r = 0; r < 2; ++r) {
        wrr[r][0] = *(const float4*)(Wg + (size_t)(32 * r) * FF_ + c0);
        wrr[r][1] = *(const float4*)(Wg + (size_t)(32 * r) * FF_ + c0 + 4);
      }
    }
    __syncthreads();
    short8 aF[2][2], bF[2];
#pragma unroll
    for (int i = 0; i < 2; ++i) {
      aF[i][0] = *(const short8*)(Osh + (16 * i + lx) * 72 + q * 8);
      aF[i][1] = *(const short8*)(Osh + (16 * i + lx) * 72 + 32 + q * 8);
    }
    bF[0] = *(const short8*)(Wsh + (16 * w + lx) * 72 + q * 8);
    bF[1] = *(const short8*)(Wsh + (16 * w + lx) * 72 + 32 + q * 8);
#pragma unroll
    for (int i = 0; i < 2; ++i) {
      acc[i] = __builtin_amdgcn_mfma_f32_16x16x32_bf16(aF[i][0], bF[0], acc[i], 0, 0, 0);
      acc[i] = __builtin_amdgcn_mfma_f32_16x16x32_bf16(aF[i][1], bF[1], acc[i], 0, 0, 0);
    }
  }

  const int o = o0 + 16 * w + lx;
  const float bias = bo[o];
#pragma unroll
  for (int i = 0; i < 2; ++i) {
    const int n = n0 + 16 * i + 4 * q;
    const float4 xv = *(const float4*)(x + ((size_t)(b * CIN_ + o)) * NTOK_ + n);
    float4 v;
    v.x = fmaxf(acc[i][0] + bias, 0.f) + xv.x;
    v.y = fmaxf(acc[i][1] + bias, 0.f) + xv.y;
    v.z = fmaxf(acc[i][2] + bias, 0.f) + xv.z;
    v.w = fmaxf(acc[i][3] + bias, 0.f) + xv.w;
    *(float4*)(pre + ((size_t)(b * COUT_ + o)) * NTOK_ + n) = v;
  }
}

// ---------------------------------------------------------------------------
// Kernel 4: BatchNorm in place, 512 threads/block (R9 form).
// ---------------------------------------------------------------------------
__global__ __launch_bounds__(512) void bn_kernel(
    float* __restrict__ out, const float* __restrict__ gamma,
    const float* __restrict__ beta) {
  __shared__ float red[16];
  const int c = blockIdx.x;
  const int tid = threadIdx.x;
  const int lane = tid & 63, w = tid >> 6;

  float4 v[2];
  float s = 0.f, s2 = 0.f;
#pragma unroll
  for (int b = 0; b < BB_; ++b) {
    float* base = out + ((size_t)(b * COUT_ + c)) * NTOK_;
    const float4 t = *(const float4*)(base + 4 * tid);
    v[b] = t;
    s += t.x + t.y + t.z + t.w;
    s2 += t.x * t.x + t.y * t.y + t.z * t.z + t.w * t.w;
  }
#pragma unroll
  for (int off = 32; off >= 1; off >>= 1) {
    s += __shfl_xor(s, off);
    s2 += __shfl_xor(s2, off);
  }
  if (lane == 0) { red[w] = s; red[8 + w] = s2; }
  __syncthreads();
  float S = 0.f, S2 = 0.f;
#pragma unroll
  for (int i = 0; i < 8; ++i) { S += red[i]; S2 += red[8 + i]; }
  const float inv = 1.0f / (float)(BB_ * NTOK_);
  const float mean = S * inv;
  const float var = S2 * inv - mean * mean;
  const float sc = rsqrtf(var + BNEPS_) * gamma[c];
  const float bt = beta[c];
#pragma unroll
  for (int b = 0; b < BB_; ++b) {
    float* base = out + ((size_t)(b * COUT_ + c)) * NTOK_;
    float4 t = v[b];
    t.x = (t.x - mean) * sc + bt;
    t.y = (t.y - mean) * sc + bt;
    t.z = (t.z - mean) * sc + bt;
    t.w = (t.w - mean) * sc + bt;
    *(float4*)(base + 4 * tid) = t;
  }
}

extern "C" void kernel_launch(void* const* d_in, const int* in_sizes, int n_in,
                              void* d_out, int out_size, void* d_ws, size_t ws_size,
                              hipStream_t stream) {
  (void)in_sizes; (void)n_in; (void)out_size; (void)ws_size;
  const float* x = (const float*)d_in[0];
  const float* WK = (const float*)d_in[1];
  const float* WQ = (const float*)d_in[2];
  const float* WV = (const float*)d_in[3];
  const float* Wo = (const float*)d_in[4];
  const float* bo = (const float*)d_in[5];
  const float* gamma = (const float*)d_in[6];
  const float* beta = (const float*)d_in[7];

  char* ws = (char*)d_ws;
  unsigned short* Kb  = (unsigned short*)(ws + 3145728);          // 4 MB
  unsigned short* Qb  = (unsigned short*)(ws + 7340032);          // 4 MB
  unsigned short* Vt  = (unsigned short*)(ws + 11534336);         // 4 MB
  unsigned short* Ob  = (unsigned short*)(ws + 15728640);         // 4 MB
  float* out = (float*)d_out;

  qkv_kernel<<<dim3(32, 4, 6), 256, 0, stream>>>(x, WK, WQ, WV, Kb, Qb, Vt);
  attn_kernel<<<dim3(512, 1, 1), 256, 0, stream>>>(Kb, Qb, Vt, Ob);
  proj_kernel<<<dim3(64, 4, 2), 256, 0, stream>>>(Ob, Wo, bo, x, out);
  bn_kernel<<<256, 512, 0, stream>>>(out, gamma, beta);
}

// Round 13
// 155.419 us; speedup vs baseline: 1.7227x; 1.2432x over previous
//
#include <hip/hip_runtime.h>
#include <math.h>

#define BB_   2
#define CIN_  256
#define NTOK_ 2048
#define FF_   512
#define COUT_ 256
#define NH_   8
#define DH_   64
#define HW_   128
#define BNEPS_ 1e-5f
#define SCALE_LOG2_ 0.09016844005556021f  /* log2(e)/16, folded into K at qkv */

typedef __attribute__((ext_vector_type(8))) short short8;
typedef __attribute__((ext_vector_type(4))) short bfx4;
typedef __attribute__((ext_vector_type(4))) float f32x4;

#if __has_builtin(__builtin_amdgcn_mfma_f32_16x16x16_bf16)
#define MFMA16(a, b, c) __builtin_amdgcn_mfma_f32_16x16x16_bf16(a, b, c, 0, 0, 0)
#else
#define MFMA16(a, b, c) __builtin_amdgcn_mfma_f32_16x16x16bf16_1k(a, b, c, 0, 0, 0)
#endif

__device__ inline unsigned short f2bf(float f) {
  union { float f; unsigned u; } v; v.f = f;
  unsigned r = (v.u + 0x7FFF + ((v.u >> 16) & 1)) >> 16;  // RNE
  return (unsigned short)r;
}

// async global->LDS DMA, 16 B per lane; LDS dest = wave-uniform base + lane*16
__device__ __forceinline__ void dma16(const unsigned short* g, unsigned short* l) {
  __builtin_amdgcn_global_load_lds(
      (const __attribute__((address_space(1))) void*)g,
      (__attribute__((address_space(3))) void*)l, 16, 0, 0);
}

// ---------------------------------------------------------------------------
// Kernel 1 (R9 form): QKV projection reading x/W fp32 directly; in-kernel
// transpose+bf16 convert; R8 coalesced epilogue. R13 addition: block (0,0,0)
// zeroes the 512 attn pair-counters (stream order guarantees visibility).
// ---------------------------------------------------------------------------
__global__ __launch_bounds__(256, 3) void qkv_kernel(
    const float* __restrict__ x, const float* __restrict__ WK,
    const float* __restrict__ WQ, const float* __restrict__ WV,
    unsigned short* __restrict__ Kb, unsigned short* __restrict__ Qb,
    unsigned short* __restrict__ Vt, unsigned* __restrict__ ctr) {
  __shared__ unsigned short Wsh[128 * 72];
  __shared__ unsigned short Xsh[64 * 72];
  __shared__ float T[64 * 65];
  const int tid = threadIdx.x;
  if (blockIdx.x == 0 && blockIdx.y == 0 && blockIdx.z == 0) {
    ctr[tid] = 0u; ctr[tid + 256] = 0u;
  }
  const int lane = tid & 63, w = tid >> 6;
  const int lx = lane & 15, q = lane >> 4;
  const int wm = w >> 1, wn = w & 1;
  const int n0 = blockIdx.x * 64;
  const int f0 = blockIdx.y * 128;
  const int b = blockIdx.z / 3, which = blockIdx.z % 3;
  const float* Wb = which == 0 ? WK : which == 1 ? WQ : WV;

  const int srow = tid >> 3;          // 0..31
  const int soff = (tid & 7) * 8;     // 0..56
  const float* Wg = Wb + (size_t)(f0 + srow) * CIN_ + soff;
  const int tc = tid >> 4;            // 0..15
  const int tn = (tid & 15) * 4;

  float4 wr[4][2], xr[4];
#pragma unroll
  for (int r = 0; r < 4; ++r) {
    wr[r][0] = *(const float4*)(Wg + (size_t)(32 * r) * CIN_);
    wr[r][1] = *(const float4*)(Wg + (size_t)(32 * r) * CIN_ + 4);
  }
#pragma unroll
  for (int p = 0; p < 4; ++p)
    xr[p] = *(const float4*)(x + (size_t)(b * CIN_ + tc + 16 * p) * NTOK_ + n0 + tn);

  f32x4 acc[4][2];
#pragma unroll
  for (int i = 0; i < 4; ++i)
#pragma unroll
    for (int j = 0; j < 2; ++j) acc[i][j] = (f32x4){0.f, 0.f, 0.f, 0.f};

  for (int kk = 0; kk < 4; ++kk) {
    __syncthreads();   // (A) previous MFMA reads done; T/Wsh writable
#pragma unroll
    for (int p = 0; p < 4; ++p) {
      const int row = tc + 16 * p;
      T[row * 65 + tn + 0] = xr[p].x; T[row * 65 + tn + 1] = xr[p].y;
      T[row * 65 + tn + 2] = xr[p].z; T[row * 65 + tn + 3] = xr[p].w;
    }
#pragma unroll
    for (int r = 0; r < 4; ++r) {
      unsigned short u[8];
      u[0] = f2bf(wr[r][0].x); u[1] = f2bf(wr[r][0].y);
      u[2] = f2bf(wr[r][0].z); u[3] = f2bf(wr[r][0].w);
      u[4] = f2bf(wr[r][1].x); u[5] = f2bf(wr[r][1].y);
      u[6] = f2bf(wr[r][1].z); u[7] = f2bf(wr[r][1].w);
      *(uint4*)(Wsh + (srow + 32 * r) * 72 + soff) = *(uint4*)u;
    }
    __syncthreads();   // (B) T ready
#pragma unroll
    for (int p = 0; p < 2; ++p) {
      const int idx = tid + 256 * p;
      const int nl = idx >> 3, c8 = (idx & 7) * 8;
      unsigned short u[8];
#pragma unroll
      for (int i = 0; i < 8; ++i) u[i] = f2bf(T[(c8 + i) * 65 + nl]);
      *(uint4*)(Xsh + nl * 72 + c8) = *(uint4*)u;
    }
    if (kk < 3) {
      const int c0 = (kk + 1) * 64;
#pragma unroll
      for (int r = 0; r < 4; ++r) {
        wr[r][0] = *(const float4*)(Wg + (size_t)(32 * r) * CIN_ + c0);
        wr[r][1] = *(const float4*)(Wg + (size_t)(32 * r) * CIN_ + c0 + 4);
      }
#pragma unroll
      for (int p = 0; p < 4; ++p)
        xr[p] = *(const float4*)(x + (size_t)(b * CIN_ + c0 + tc + 16 * p) * NTOK_ + n0 + tn);
    }
    __syncthreads();   // (C) Xsh/Wsh ready
    short8 xF[2][2];
#pragma unroll
    for (int i = 0; i < 2; ++i) {
      xF[i][0] = *(const short8*)(Xsh + (32 * wn + 16 * i + lx) * 72 + q * 8);
      xF[i][1] = *(const short8*)(Xsh + (32 * wn + 16 * i + lx) * 72 + 32 + q * 8);
    }
    if (which < 2) {
#pragma unroll
      for (int i = 0; i < 4; ++i) {
        const short8 w0 = *(const short8*)(Wsh + (64 * wm + 16 * i + lx) * 72 + q * 8);
        const short8 w1 = *(const short8*)(Wsh + (64 * wm + 16 * i + lx) * 72 + 32 + q * 8);
#pragma unroll
        for (int j = 0; j < 2; ++j) {
          acc[i][j] = __builtin_amdgcn_mfma_f32_16x16x32_bf16(w0, xF[j][0], acc[i][j], 0, 0, 0);
          acc[i][j] = __builtin_amdgcn_mfma_f32_16x16x32_bf16(w1, xF[j][1], acc[i][j], 0, 0, 0);
        }
      }
    } else {
#pragma unroll
      for (int jf = 0; jf < 4; ++jf) {
        const short8 w0 = *(const short8*)(Wsh + (64 * wm + 16 * jf + lx) * 72 + q * 8);
        const short8 w1 = *(const short8*)(Wsh + (64 * wm + 16 * jf + lx) * 72 + 32 + q * 8);
#pragma unroll
        for (int i = 0; i < 2; ++i) {
          acc[jf][i] = __builtin_amdgcn_mfma_f32_16x16x32_bf16(xF[i][0], w0, acc[jf][i], 0, 0, 0);
          acc[jf][i] = __builtin_amdgcn_mfma_f32_16x16x32_bf16(xF[i][1], w1, acc[jf][i], 0, 0, 0);
        }
      }
    }
  }

  // ---- coalesced epilogue (R8)
  __syncthreads();

  if (which < 2) {
    const float sc = (which == 0) ? SCALE_LOG2_ : 1.0f;
#pragma unroll
    for (int i = 0; i < 4; ++i)
#pragma unroll
      for (int j = 0; j < 2; ++j) {
        const int row = wm * 64 + 32 * wn + 16 * j + lx;
        const int d0 = 16 * i + 4 * q;
        ushort4 u;
        u.x = f2bf(acc[i][j][0] * sc); u.y = f2bf(acc[i][j][1] * sc);
        u.z = f2bf(acc[i][j][2] * sc); u.w = f2bf(acc[i][j][3] * sc);
        *(ushort4*)(Wsh + row * 72 + d0) = u;
      }
  } else {
#pragma unroll
    for (int jf = 0; jf < 4; ++jf)
#pragma unroll
      for (int i = 0; i < 2; ++i) {
        const int row = wm * 64 + 16 * jf + lx;
        const int nc = 32 * wn + 16 * i + 4 * q;
        ushort4 u;
        u.x = f2bf(acc[jf][i][0]); u.y = f2bf(acc[jf][i][1]);
        u.z = f2bf(acc[jf][i][2]); u.w = f2bf(acc[jf][i][3]);
        *(ushort4*)(Wsh + row * 72 + nc) = u;
      }
  }
  __syncthreads();

  const int h0 = f0 >> 6;
  if (which < 2) {
    unsigned short* Y = (which == 0 ? Kb : Qb);
#pragma unroll
    for (int p = 0; p < 4; ++p) {
      const int idx = tid + 256 * p;
      const int row = idx >> 3;
      const int c = (idx & 7) * 8;
      const uint4 val = *(const uint4*)(Wsh + row * 72 + c);
      *(uint4*)(Y + ((size_t)((b * NH_ + h0 + (row >> 6)) * NTOK_ + n0 + (row & 63))) * DH_ + c) = val;
    }
  } else {
#pragma unroll
    for (int p = 0; p < 4; ++p) {
      const int idx = tid + 256 * p;
      const int row = idx >> 3;
      const int c = (idx & 7) * 8;
      const uint4 val = *(const uint4*)(Wsh + row * 72 + c);
      *(uint4*)(Vt + ((size_t)((b * NH_ + h0 + (row >> 6)) * DH_ + (row & 63))) * NTOK_ + n0 + c) = val;
    }
  }
}

// ---------------------------------------------------------------------------
// Kernel 2 (R13): attention with split-softmax load balancing. R11 counters
// showed Occupancy 14% — CU busy time ∝ njt (1..16) while avg is 8.5 (tail
// imbalance), since co-resident blocks share iblk. Because this softmax has
// NO running max, o and rs are plain sums -> j-halves combine by ADDITION.
// Each (bh,iblk) = 2 blocks: half 0 takes jt [0,ceil(njt/2)), half 1 the
// rest (<=8 tiles each). Both write per-lane partials; fetch_add(ACQ_REL) on
// a per-pair counter (zeroed by qkv); the SECOND arrival combines + writes Ob.
// No spinning, no dispatch-order assumption, deadlock-free. LDS path = R9.
// ---------------------------------------------------------------------------
__global__ __launch_bounds__(256, 2) void attn_kernel(
    const unsigned short* __restrict__ Kb, const unsigned short* __restrict__ Qb,
    const unsigned short* __restrict__ Vt, unsigned short* __restrict__ Ob,
    float* __restrict__ oPart, float* __restrict__ rsPart,
    unsigned* __restrict__ ctr) {
  __shared__ __align__(16) unsigned short Qbuf[2][8192];
  __shared__ __align__(16) unsigned short Vbuf[2][8192];
  __shared__ unsigned tksh;

  const int tid = threadIdx.x;
  const int lane = tid & 63;
  const int w = tid >> 6;
  const int lx = lane & 15;
  const int g = lane >> 4;

  const int bid = blockIdx.x;        // 0..1023
  const int pid = bid >> 1;          // pair id 0..511
  const int half = bid & 1;
  const int bh = pid >> 5;           // 0..15
  const int iblk = pid & 31;
  const int h = bh & 7, b = bh >> 3;
  const int i0 = iblk * 64;
  const int njt = (iblk >> 1) + 1;           // 1..16
  const int nh = (njt + 1) >> 1;             // half0 tile count (<=8)
  const int jbeg = half ? nh : 0;
  const int jend = half ? njt : nh;          // half1 may be empty (njt==1)

  const size_t bhs = (size_t)b * NH_ + h;
  const unsigned short* Kg = Kb + bhs * (size_t)NTOK_ * DH_ + (size_t)i0 * DH_;
  const unsigned short* Qg = Qb + bhs * (size_t)NTOK_ * DH_;
  const unsigned short* Vg = Vt + bhs * (size_t)DH_ * NTOK_;

  auto stage = [&](int buf, int j0) {
#pragma unroll
    for (int cc = 0; cc < 4; ++cc) {
      const int chunk = 4 * w + cc;
      {  // Q
        const int row = chunk * 8 + (lane >> 3);
        const int grp = (lane & 7) ^ (row & 7);
        dma16(Qg + (size_t)(j0 + row) * DH_ + grp * 8, &Qbuf[buf][chunk * 512]);
      }
      {  // V
        const int row = chunk * 4 + (lane >> 4);
        const int grp = (lane & 15) ^ (row & 7);
        dma16(Vg + (size_t)row * NTOK_ + j0 + grp * 8, &Vbuf[buf][chunk * 512]);
      }
    }
  };

  f32x4 o[4];
#pragma unroll
  for (int t = 0; t < 4; ++t) o[t] = (f32x4){0.f, 0.f, 0.f, 0.f};
  float rs = 0.f;

  if (jbeg < jend) {
    const short8 aK0 = *(const short8*)(Kg + (16 * w + lx) * DH_ + g * 8);
    const short8 aK1 = *(const short8*)(Kg + (16 * w + lx) * DH_ + 32 + g * 8);
    const int fr0 = ((g ^ (lx & 7)) << 3);
    const int fr1 = (((4 + g) ^ (lx & 7)) << 3);

    stage(0, jbeg * 128);
    __syncthreads();   // drains DMA

    int cur = 0;
    for (int jt = jbeg; jt < jend; ++jt) {
      if (jt + 1 < jend) stage(cur ^ 1, (jt + 1) * 128);

      const unsigned short* Qs = Qbuf[cur];
      const unsigned short* Vs = Vbuf[cur];

      f32x4 sa[8];
#pragma unroll
      for (int s = 0; s < 8; ++s) {
        const int row = 16 * s + lx;
        const short8 a0 = *(const short8*)(Qs + row * 64 + fr0);
        const short8 a1 = *(const short8*)(Qs + row * 64 + fr1);
        sa[s] = (f32x4){0.f, 0.f, 0.f, 0.f};
        sa[s] = __builtin_amdgcn_mfma_f32_16x16x32_bf16(a0, aK0, sa[s], 0, 0, 0);
        sa[s] = __builtin_amdgcn_mfma_f32_16x16x32_bf16(a1, aK1, sa[s], 0, 0, 0);
      }

#pragma unroll
      for (int s = 0; s < 8; ++s) {
        const float p0 = __builtin_amdgcn_exp2f(sa[s][0]);
        const float p1 = __builtin_amdgcn_exp2f(sa[s][1]);
        const float p2 = __builtin_amdgcn_exp2f(sa[s][2]);
        const float p3 = __builtin_amdgcn_exp2f(sa[s][3]);
        rs += (p0 + p1) + (p2 + p3);
        union { unsigned u[2]; bfx4 v; } pk;
        pk.u[0] = (__builtin_bit_cast(unsigned, p0) >> 16) |
                  (__builtin_bit_cast(unsigned, p1) & 0xFFFF0000u);
        pk.u[1] = (__builtin_bit_cast(unsigned, p2) >> 16) |
                  (__builtin_bit_cast(unsigned, p3) & 0xFFFF0000u);
        const int jgrp = 2 * s + (g >> 1);
        const int joff = (g & 1) << 2;
#pragma unroll
        for (int t = 0; t < 4; ++t) {
          const int row = 16 * t + lx;
          const bfx4 va = *(const bfx4*)(Vs + row * 128 +
                                         ((jgrp ^ (row & 7)) << 3) + joff);
          o[t] = MFMA16(va, pk.v, o[t]);
        }
      }

      __syncthreads();
      cur ^= 1;
    }
  }

  // ---- write per-lane partials, then last-arrival combines ----
#pragma unroll
  for (int t = 0; t < 4; ++t)
    *(f32x4*)(oPart + (size_t)bid * 4096 + tid * 16 + t * 4) = o[t];
  rsPart[(size_t)bid * 256 + tid] = rs;
  __syncthreads();   // all partial stores complete (vmcnt drained)
  if (tid == 0) {
    tksh = __hip_atomic_fetch_add(&ctr[pid], 1u, __ATOMIC_ACQ_REL,
                                  __HIP_MEMORY_SCOPE_AGENT);
  }
  __syncthreads();
  if (tksh == 0) return;             // first arrival exits

  // second arrival: add partner partials (acquire via the RMW above)
  const int pbid = bid ^ 1;
#pragma unroll
  for (int t = 0; t < 4; ++t) {
    const f32x4 po = *(const f32x4*)(oPart + (size_t)pbid * 4096 + tid * 16 + t * 4);
    o[t][0] += po[0]; o[t][1] += po[1]; o[t][2] += po[2]; o[t][3] += po[3];
  }
  rs += rsPart[(size_t)pbid * 256 + tid];

  rs += __shfl_xor(rs, 16);
  rs += __shfl_xor(rs, 32);
  const float invl = 1.0f / rs;
  const int n = i0 + 16 * w + lx;
#pragma unroll
  for (int t = 0; t < 4; ++t) {
    ushort4 uo;
    uo.x = f2bf(o[t][0] * invl); uo.y = f2bf(o[t][1] * invl);
    uo.z = f2bf(o[t][2] * invl); uo.w = f2bf(o[t][3] * invl);
    *(ushort4*)(Ob + ((size_t)(b * NTOK_ + n)) * FF_ + h * 64 + 16 * t + 4 * g) = uo;
  }
}

// ---------------------------------------------------------------------------
// Kernel 3: output projection + bias + ReLU + skip -> d_out fp32 (R9 form).
// ---------------------------------------------------------------------------
__global__ __launch_bounds__(256, 2) void proj_kernel(
    const unsigned short* __restrict__ Ob, const float* __restrict__ Wo,
    const float* __restrict__ bo, const float* __restrict__ x,
    float* __restrict__ pre) {
  __shared__ unsigned short Osh[32 * 72];
  __shared__ unsigned short Wsh[64 * 72];
  const int tid = threadIdx.x;
  const int lane = tid & 63, w = tid >> 6;
  const int lx = lane & 15, q = lane >> 4;
  const int n0 = blockIdx.x * 32;
  const int o0 = blockIdx.y * 64;
  const int b = blockIdx.z;

  const int srow = tid >> 3;
  const int soff = (tid & 7) * 8;
  const unsigned short* Og = Ob + ((size_t)(b * NTOK_ + n0 + srow)) * FF_ + soff;
  const float* Wg = Wo + (size_t)(o0 + srow) * FF_ + soff;

  uint4 orr;
  float4 wrr[2][2];
  orr = *(const uint4*)(Og);
#pragma unroll
  for (int r = 0; r < 2; ++r) {
    wrr[r][0] = *(const float4*)(Wg + (size_t)(32 * r) * FF_);
    wrr[r][1] = *(const float4*)(Wg + (size_t)(32 * r) * FF_ + 4);
  }

  f32x4 acc[2];
#pragma unroll
  for (int i = 0; i < 2; ++i) acc[i] = (f32x4){0.f, 0.f, 0.f, 0.f};

  for (int kk = 0; kk < 8; ++kk) {
    __syncthreads();
    *(uint4*)(Osh + srow * 72 + soff) = orr;
#pragma unroll
    for (int r = 0; r < 2; ++r) {
      unsigned short u[8];
      u[0] = f2bf(wrr[r][0].x); u[1] = f2bf(wrr[r][0].y);
      u[2] = f2bf(wrr[r][0].z); u[3] = f2bf(wrr[r][0].w);
      u[4] = f2bf(wrr[r][1].x); u[5] = f2bf(wrr[r][1].y);
      u[6] = f2bf(wrr[r][1].z); u[7] = f2bf(wrr[r][1].w);
      *(uint4*)(Wsh + (srow + 32 * r) * 72 + soff) = *(uint4*)u;
    }
    if (kk < 7) {
      const int c0 = (kk + 1) * 64;
      orr = *(const uint4*)(Og + c0);
#pragma unroll
      for (int r = 0; r < 2; ++r) {
        wrr[r][0] = *(const float4*)(Wg + (size_t)(32 * r) * FF_ + c0);
        wrr[r][1] = *(const float4*)(Wg + (size_t)(32 * r) * FF_ + c0 + 4);
      }
    }
    __syncthreads();
    short8 aF[2][2], bF[2];
#pragma unroll
    for (int i = 0; i < 2; ++i) {
      aF[i][0] = *(const short8*)(Osh + (16 * i + lx) * 72 + q * 8);
      aF[i][1] = *(const short8*)(Osh + (16 * i + lx) * 72 + 32 + q * 8);
    }
    bF[0] = *(const short8*)(Wsh + (16 * w + lx) * 72 + q * 8);
    bF[1] = *(const short8*)(Wsh + (16 * w + lx) * 72 + 32 + q * 8);
#pragma unroll
    for (int i = 0; i < 2; ++i) {
      acc[i] = __builtin_amdgcn_mfma_f32_16x16x32_bf16(aF[i][0], bF[0], acc[i], 0, 0, 0);
      acc[i] = __builtin_amdgcn_mfma_f32_16x16x32_bf16(aF[i][1], bF[1], acc[i], 0, 0, 0);
    }
  }

  const int o = o0 + 16 * w + lx;
  const float bias = bo[o];
#pragma unroll
  for (int i = 0; i < 2; ++i) {
    const int n = n0 + 16 * i + 4 * q;
    const float4 xv = *(const float4*)(x + ((size_t)(b * CIN_ + o)) * NTOK_ + n);
    float4 v;
    v.x = fmaxf(acc[i][0] + bias, 0.f) + xv.x;
    v.y = fmaxf(acc[i][1] + bias, 0.f) + xv.y;
    v.z = fmaxf(acc[i][2] + bias, 0.f) + xv.z;
    v.w = fmaxf(acc[i][3] + bias, 0.f) + xv.w;
    *(float4*)(pre + ((size_t)(b * COUT_ + o)) * NTOK_ + n) = v;
  }
}

// ---------------------------------------------------------------------------
// Kernel 4: BatchNorm in place, 512 threads/block (R9 form).
// ---------------------------------------------------------------------------
__global__ __launch_bounds__(512) void bn_kernel(
    float* __restrict__ out, const float* __restrict__ gamma,
    const float* __restrict__ beta) {
  __shared__ float red[16];
  const int c = blockIdx.x;
  const int tid = threadIdx.x;
  const int lane = tid & 63, w = tid >> 6;

  float4 v[2];
  float s = 0.f, s2 = 0.f;
#pragma unroll
  for (int b = 0; b < BB_; ++b) {
    float* base = out + ((size_t)(b * COUT_ + c)) * NTOK_;
    const float4 t = *(const float4*)(base + 4 * tid);
    v[b] = t;
    s += t.x + t.y + t.z + t.w;
    s2 += t.x * t.x + t.y * t.y + t.z * t.z + t.w * t.w;
  }
#pragma unroll
  for (int off = 32; off >= 1; off >>= 1) {
    s += __shfl_xor(s, off);
    s2 += __shfl_xor(s2, off);
  }
  if (lane == 0) { red[w] = s; red[8 + w] = s2; }
  __syncthreads();
  float S = 0.f, S2 = 0.f;
#pragma unroll
  for (int i = 0; i < 8; ++i) { S += red[i]; S2 += red[8 + i]; }
  const float inv = 1.0f / (float)(BB_ * NTOK_);
  const float mean = S * inv;
  const float var = S2 * inv - mean * mean;
  const float sc = rsqrtf(var + BNEPS_) * gamma[c];
  const float bt = beta[c];
#pragma unroll
  for (int b = 0; b < BB_; ++b) {
    float* base = out + ((size_t)(b * COUT_ + c)) * NTOK_;
    float4 t = v[b];
    t.x = (t.x - mean) * sc + bt;
    t.y = (t.y - mean) * sc + bt;
    t.z = (t.z - mean) * sc + bt;
    t.w = (t.w - mean) * sc + bt;
    *(float4*)(base + 4 * tid) = t;
  }
}

extern "C" void kernel_launch(void* const* d_in, const int* in_sizes, int n_in,
                              void* d_out, int out_size, void* d_ws, size_t ws_size,
                              hipStream_t stream) {
  (void)in_sizes; (void)n_in; (void)out_size; (void)ws_size;
  const float* x = (const float*)d_in[0];
  const float* WK = (const float*)d_in[1];
  const float* WQ = (const float*)d_in[2];
  const float* WV = (const float*)d_in[3];
  const float* Wo = (const float*)d_in[4];
  const float* bo = (const float*)d_in[5];
  const float* gamma = (const float*)d_in[6];
  const float* beta = (const float*)d_in[7];

  char* ws = (char*)d_ws;
  unsigned short* Kb  = (unsigned short*)(ws + 3145728);          // 4 MB
  unsigned short* Qb  = (unsigned short*)(ws + 7340032);          // 4 MB
  unsigned short* Vt  = (unsigned short*)(ws + 11534336);         // 4 MB
  unsigned short* Ob  = (unsigned short*)(ws + 15728640);         // 4 MB
  float* oPart        = (float*)(ws + 33554432);                  // 16 MB
  float* rsPart       = (float*)(ws + 52428800);                  // 1 MB
  unsigned* ctr       = (unsigned*)(ws + 54525952);               // 2 KB
  float* out = (float*)d_out;

  qkv_kernel<<<dim3(32, 4, 6), 256, 0, stream>>>(x, WK, WQ, WV, Kb, Qb, Vt, ctr);
  attn_kernel<<<dim3(1024, 1, 1), 256, 0, stream>>>(Kb, Qb, Vt, Ob,
                                                    oPart, rsPart, ctr);
  proj_kernel<<<dim3(64, 4, 2), 256, 0, stream>>>(Ob, Wo, bo, x, out);
  bn_kernel<<<256, 512, 0, stream>>>(out, gamma, beta);
}

// Round 14
// 119.946 us; speedup vs baseline: 2.2322x; 1.2957x over previous
//
#include <hip/hip_runtime.h>
#include <math.h>

#define BB_   2
#define CIN_  256
#define NTOK_ 2048
#define FF_   512
#define COUT_ 256
#define NH_   8
#define DH_   64
#define HW_   128
#define BNEPS_ 1e-5f
#define SCALE_LOG2_ 0.09016844005556021f  /* log2(e)/16, folded into K at qkv */

typedef __attribute__((ext_vector_type(8))) short short8;
typedef __attribute__((ext_vector_type(4))) short bfx4;
typedef __attribute__((ext_vector_type(4))) float f32x4;

#if __has_builtin(__builtin_amdgcn_mfma_f32_16x16x16_bf16)
#define MFMA16(a, b, c) __builtin_amdgcn_mfma_f32_16x16x16_bf16(a, b, c, 0, 0, 0)
#else
#define MFMA16(a, b, c) __builtin_amdgcn_mfma_f32_16x16x16bf16_1k(a, b, c, 0, 0, 0)
#endif

__device__ inline unsigned short f2bf(float f) {
  union { float f; unsigned u; } v; v.f = f;
  unsigned r = (v.u + 0x7FFF + ((v.u >> 16) & 1)) >> 16;  // RNE
  return (unsigned short)r;
}

// async global->LDS DMA, 16 B per lane; LDS dest = wave-uniform base + lane*16
__device__ __forceinline__ void dma16(const unsigned short* g, unsigned short* l) {
  __builtin_amdgcn_global_load_lds(
      (const __attribute__((address_space(1))) void*)g,
      (__attribute__((address_space(3))) void*)l, 16, 0, 0);
}

// ---------------------------------------------------------------------------
// Kernel 1 (R9): QKV projection reading x/W fp32 directly; in-kernel
// transpose+bf16 convert (bit-identical to old prep); R8 coalesced epilogue.
// ---------------------------------------------------------------------------
__global__ __launch_bounds__(256, 3) void qkv_kernel(
    const float* __restrict__ x, const float* __restrict__ WK,
    const float* __restrict__ WQ, const float* __restrict__ WV,
    unsigned short* __restrict__ Kb, unsigned short* __restrict__ Qb,
    unsigned short* __restrict__ Vt) {
  __shared__ unsigned short Wsh[128 * 72];
  __shared__ unsigned short Xsh[64 * 72];
  __shared__ float T[64 * 65];
  const int tid = threadIdx.x;
  const int lane = tid & 63, w = tid >> 6;
  const int lx = lane & 15, q = lane >> 4;
  const int wm = w >> 1, wn = w & 1;
  const int n0 = blockIdx.x * 64;
  const int f0 = blockIdx.y * 128;
  const int b = blockIdx.z / 3, which = blockIdx.z % 3;
  const float* Wb = which == 0 ? WK : which == 1 ? WQ : WV;

  const int srow = tid >> 3;          // 0..31
  const int soff = (tid & 7) * 8;     // 0..56
  const float* Wg = Wb + (size_t)(f0 + srow) * CIN_ + soff;
  const int tc = tid >> 4;            // 0..15
  const int tn = (tid & 15) * 4;

  float4 wr[4][2], xr[4];
#pragma unroll
  for (int r = 0; r < 4; ++r) {
    wr[r][0] = *(const float4*)(Wg + (size_t)(32 * r) * CIN_);
    wr[r][1] = *(const float4*)(Wg + (size_t)(32 * r) * CIN_ + 4);
  }
#pragma unroll
  for (int p = 0; p < 4; ++p)
    xr[p] = *(const float4*)(x + (size_t)(b * CIN_ + tc + 16 * p) * NTOK_ + n0 + tn);

  f32x4 acc[4][2];
#pragma unroll
  for (int i = 0; i < 4; ++i)
#pragma unroll
    for (int j = 0; j < 2; ++j) acc[i][j] = (f32x4){0.f, 0.f, 0.f, 0.f};

  for (int kk = 0; kk < 4; ++kk) {
    __syncthreads();   // (A) previous MFMA reads done; T/Wsh writable
#pragma unroll
    for (int p = 0; p < 4; ++p) {
      const int row = tc + 16 * p;
      T[row * 65 + tn + 0] = xr[p].x; T[row * 65 + tn + 1] = xr[p].y;
      T[row * 65 + tn + 2] = xr[p].z; T[row * 65 + tn + 3] = xr[p].w;
    }
#pragma unroll
    for (int r = 0; r < 4; ++r) {
      unsigned short u[8];
      u[0] = f2bf(wr[r][0].x); u[1] = f2bf(wr[r][0].y);
      u[2] = f2bf(wr[r][0].z); u[3] = f2bf(wr[r][0].w);
      u[4] = f2bf(wr[r][1].x); u[5] = f2bf(wr[r][1].y);
      u[6] = f2bf(wr[r][1].z); u[7] = f2bf(wr[r][1].w);
      *(uint4*)(Wsh + (srow + 32 * r) * 72 + soff) = *(uint4*)u;
    }
    __syncthreads();   // (B) T ready
#pragma unroll
    for (int p = 0; p < 2; ++p) {
      const int idx = tid + 256 * p;
      const int nl = idx >> 3, c8 = (idx & 7) * 8;
      unsigned short u[8];
#pragma unroll
      for (int i = 0; i < 8; ++i) u[i] = f2bf(T[(c8 + i) * 65 + nl]);
      *(uint4*)(Xsh + nl * 72 + c8) = *(uint4*)u;
    }
    if (kk < 3) {
      const int c0 = (kk + 1) * 64;
#pragma unroll
      for (int r = 0; r < 4; ++r) {
        wr[r][0] = *(const float4*)(Wg + (size_t)(32 * r) * CIN_ + c0);
        wr[r][1] = *(const float4*)(Wg + (size_t)(32 * r) * CIN_ + c0 + 4);
      }
#pragma unroll
      for (int p = 0; p < 4; ++p)
        xr[p] = *(const float4*)(x + (size_t)(b * CIN_ + c0 + tc + 16 * p) * NTOK_ + n0 + tn);
    }
    __syncthreads();   // (C) Xsh/Wsh ready
    short8 xF[2][2];
#pragma unroll
    for (int i = 0; i < 2; ++i) {
      xF[i][0] = *(const short8*)(Xsh + (32 * wn + 16 * i + lx) * 72 + q * 8);
      xF[i][1] = *(const short8*)(Xsh + (32 * wn + 16 * i + lx) * 72 + 32 + q * 8);
    }
    if (which < 2) {
#pragma unroll
      for (int i = 0; i < 4; ++i) {
        const short8 w0 = *(const short8*)(Wsh + (64 * wm + 16 * i + lx) * 72 + q * 8);
        const short8 w1 = *(const short8*)(Wsh + (64 * wm + 16 * i + lx) * 72 + 32 + q * 8);
#pragma unroll
        for (int j = 0; j < 2; ++j) {
          acc[i][j] = __builtin_amdgcn_mfma_f32_16x16x32_bf16(w0, xF[j][0], acc[i][j], 0, 0, 0);
          acc[i][j] = __builtin_amdgcn_mfma_f32_16x16x32_bf16(w1, xF[j][1], acc[i][j], 0, 0, 0);
        }
      }
    } else {
#pragma unroll
      for (int jf = 0; jf < 4; ++jf) {
        const short8 w0 = *(const short8*)(Wsh + (64 * wm + 16 * jf + lx) * 72 + q * 8);
        const short8 w1 = *(const short8*)(Wsh + (64 * wm + 16 * jf + lx) * 72 + 32 + q * 8);
#pragma unroll
        for (int i = 0; i < 2; ++i) {
          acc[jf][i] = __builtin_amdgcn_mfma_f32_16x16x32_bf16(xF[i][0], w0, acc[jf][i], 0, 0, 0);
          acc[jf][i] = __builtin_amdgcn_mfma_f32_16x16x32_bf16(xF[i][1], w1, acc[jf][i], 0, 0, 0);
        }
      }
    }
  }

  // ---- coalesced epilogue (R8)
  __syncthreads();

  if (which < 2) {
    const float sc = (which == 0) ? SCALE_LOG2_ : 1.0f;
#pragma unroll
    for (int i = 0; i < 4; ++i)
#pragma unroll
      for (int j = 0; j < 2; ++j) {
        const int row = wm * 64 + 32 * wn + 16 * j + lx;
        const int d0 = 16 * i + 4 * q;
        ushort4 u;
        u.x = f2bf(acc[i][j][0] * sc); u.y = f2bf(acc[i][j][1] * sc);
        u.z = f2bf(acc[i][j][2] * sc); u.w = f2bf(acc[i][j][3] * sc);
        *(ushort4*)(Wsh + row * 72 + d0) = u;
      }
  } else {
#pragma unroll
    for (int jf = 0; jf < 4; ++jf)
#pragma unroll
      for (int i = 0; i < 2; ++i) {
        const int row = wm * 64 + 16 * jf + lx;
        const int nc = 32 * wn + 16 * i + 4 * q;
        ushort4 u;
        u.x = f2bf(acc[jf][i][0]); u.y = f2bf(acc[jf][i][1]);
        u.z = f2bf(acc[jf][i][2]); u.w = f2bf(acc[jf][i][3]);
        *(ushort4*)(Wsh + row * 72 + nc) = u;
      }
  }
  __syncthreads();

  const int h0 = f0 >> 6;
  if (which < 2) {
    unsigned short* Y = (which == 0 ? Kb : Qb);
#pragma unroll
    for (int p = 0; p < 4; ++p) {
      const int idx = tid + 256 * p;
      const int row = idx >> 3;
      const int c = (idx & 7) * 8;
      const uint4 val = *(const uint4*)(Wsh + row * 72 + c);
      *(uint4*)(Y + ((size_t)((b * NH_ + h0 + (row >> 6)) * NTOK_ + n0 + (row & 63))) * DH_ + c) = val;
    }
  } else {
#pragma unroll
    for (int p = 0; p < 4; ++p) {
      const int idx = tid + 256 * p;
      const int row = idx >> 3;
      const int c = (idx & 7) * 8;
      const uint4 val = *(const uint4*)(Wsh + row * 72 + c);
      *(uint4*)(Vt + ((size_t)((b * NH_ + h0 + (row >> 6)) * DH_ + (row & 63))) * NTOK_ + n0 + c) = val;
    }
  }
}

// ---------------------------------------------------------------------------
// Kernel 2 (R9): block-causal attention — S^T trick, DMA dbuf, XCD grouping,
// LPT pairing. R12 (no-LDS: 100us) and R13 (split-softmax: 66us) both proved
// this 22us structure locally optimal — LDS staging provides the coalescing.
// ---------------------------------------------------------------------------
__global__ __launch_bounds__(256, 2) void attn_kernel(
    const unsigned short* __restrict__ Kb, const unsigned short* __restrict__ Qb,
    const unsigned short* __restrict__ Vt, unsigned short* __restrict__ Ob) {
  __shared__ __align__(16) unsigned short Qbuf[2][8192];
  __shared__ __align__(16) unsigned short Vbuf[2][8192];

  const int tid = threadIdx.x;
  const int lane = tid & 63;
  const int w = tid >> 6;
  const int lx = lane & 15;
  const int g = lane >> 4;

  const int bid = blockIdx.x;
  const int xcd = bid & 7;
  const int k = bid >> 3;
  const int bh = xcd * 2 + (k & 1);
  const int u = k >> 1;
  const int iblk = (u < 16) ? (31 - u) : (u - 16);
  const int h = bh & 7, b = bh >> 3;
  const int i0 = iblk * 64;
  const int njt = (iblk >> 1) + 1;

  const size_t bhs = (size_t)b * NH_ + h;
  const unsigned short* Kg = Kb + bhs * (size_t)NTOK_ * DH_ + (size_t)i0 * DH_;
  const unsigned short* Qg = Qb + bhs * (size_t)NTOK_ * DH_;
  const unsigned short* Vg = Vt + bhs * (size_t)DH_ * NTOK_;

  auto stage = [&](int buf, int j0) {
#pragma unroll
    for (int cc = 0; cc < 4; ++cc) {
      const int chunk = 4 * w + cc;
      {  // Q
        const int row = chunk * 8 + (lane >> 3);
        const int grp = (lane & 7) ^ (row & 7);
        dma16(Qg + (size_t)(j0 + row) * DH_ + grp * 8, &Qbuf[buf][chunk * 512]);
      }
      {  // V
        const int row = chunk * 4 + (lane >> 4);
        const int grp = (lane & 15) ^ (row & 7);
        dma16(Vg + (size_t)row * NTOK_ + j0 + grp * 8, &Vbuf[buf][chunk * 512]);
      }
    }
  };

  const short8 aK0 = *(const short8*)(Kg + (16 * w + lx) * DH_ + g * 8);
  const short8 aK1 = *(const short8*)(Kg + (16 * w + lx) * DH_ + 32 + g * 8);

  f32x4 o[4];
#pragma unroll
  for (int t = 0; t < 4; ++t) o[t] = (f32x4){0.f, 0.f, 0.f, 0.f};
  float rs = 0.f;

  const int fr0 = ((g ^ (lx & 7)) << 3);
  const int fr1 = (((4 + g) ^ (lx & 7)) << 3);

  stage(0, 0);
  __syncthreads();

  int cur = 0;
  for (int jt = 0; jt < njt; ++jt) {
    if (jt + 1 < njt) stage(cur ^ 1, (jt + 1) * 128);

    const unsigned short* Qs = Qbuf[cur];
    const unsigned short* Vs = Vbuf[cur];

    f32x4 sa[8];
#pragma unroll
    for (int s = 0; s < 8; ++s) {
      const int row = 16 * s + lx;
      const short8 a0 = *(const short8*)(Qs + row * 64 + fr0);
      const short8 a1 = *(const short8*)(Qs + row * 64 + fr1);
      sa[s] = (f32x4){0.f, 0.f, 0.f, 0.f};
      sa[s] = __builtin_amdgcn_mfma_f32_16x16x32_bf16(a0, aK0, sa[s], 0, 0, 0);
      sa[s] = __builtin_amdgcn_mfma_f32_16x16x32_bf16(a1, aK1, sa[s], 0, 0, 0);
    }

#pragma unroll
    for (int s = 0; s < 8; ++s) {
      const float p0 = __builtin_amdgcn_exp2f(sa[s][0]);
      const float p1 = __builtin_amdgcn_exp2f(sa[s][1]);
      const float p2 = __builtin_amdgcn_exp2f(sa[s][2]);
      const float p3 = __builtin_amdgcn_exp2f(sa[s][3]);
      rs += (p0 + p1) + (p2 + p3);
      union { unsigned u[2]; bfx4 v; } pk;
      pk.u[0] = (__builtin_bit_cast(unsigned, p0) >> 16) |
                (__builtin_bit_cast(unsigned, p1) & 0xFFFF0000u);
      pk.u[1] = (__builtin_bit_cast(unsigned, p2) >> 16) |
                (__builtin_bit_cast(unsigned, p3) & 0xFFFF0000u);
      const int jgrp = 2 * s + (g >> 1);
      const int joff = (g & 1) << 2;
#pragma unroll
      for (int t = 0; t < 4; ++t) {
        const int row = 16 * t + lx;
        const bfx4 va = *(const bfx4*)(Vs + row * 128 +
                                       ((jgrp ^ (row & 7)) << 3) + joff);
        o[t] = MFMA16(va, pk.v, o[t]);
      }
    }

    __syncthreads();
    cur ^= 1;
  }

  rs += __shfl_xor(rs, 16);
  rs += __shfl_xor(rs, 32);
  const float invl = 1.0f / rs;
  const int n = i0 + 16 * w + lx;
#pragma unroll
  for (int t = 0; t < 4; ++t) {
    ushort4 uo;
    uo.x = f2bf(o[t][0] * invl); uo.y = f2bf(o[t][1] * invl);
    uo.z = f2bf(o[t][2] * invl); uo.w = f2bf(o[t][3] * invl);
    *(ushort4*)(Ob + ((size_t)(b * NTOK_ + n)) * FF_ + h * 64 + 16 * t + 4 * g) = uo;
  }
}

// ---------------------------------------------------------------------------
// Kernel 3 (R9): output projection + bias + ReLU + skip -> d_out fp32.
// ---------------------------------------------------------------------------
__global__ __launch_bounds__(256, 2) void proj_kernel(
    const unsigned short* __restrict__ Ob, const float* __restrict__ Wo,
    const float* __restrict__ bo, const float* __restrict__ x,
    float* __restrict__ pre) {
  __shared__ unsigned short Osh[32 * 72];
  __shared__ unsigned short Wsh[64 * 72];
  const int tid = threadIdx.x;
  const int lane = tid & 63, w = tid >> 6;
  const int lx = lane & 15, q = lane >> 4;
  const int n0 = blockIdx.x * 32;
  const int o0 = blockIdx.y * 64;
  const int b = blockIdx.z;

  const int srow = tid >> 3;
  const int soff = (tid & 7) * 8;
  const unsigned short* Og = Ob + ((size_t)(b * NTOK_ + n0 + srow)) * FF_ + soff;
  const float* Wg = Wo + (size_t)(o0 + srow) * FF_ + soff;

  uint4 orr;
  float4 wrr[2][2];
  orr = *(const uint4*)(Og);
#pragma unroll
  for (int r = 0; r < 2; ++r) {
    wrr[r][0] = *(const float4*)(Wg + (size_t)(32 * r) * FF_);
    wrr[r][1] = *(const float4*)(Wg + (size_t)(32 * r) * FF_ + 4);
  }

  f32x4 acc[2];
#pragma unroll
  for (int i = 0; i < 2; ++i) acc[i] = (f32x4){0.f, 0.f, 0.f, 0.f};

  for (int kk = 0; kk < 8; ++kk) {
    __syncthreads();
    *(uint4*)(Osh + srow * 72 + soff) = orr;
#pragma unroll
    for (int r = 0; r < 2; ++r) {
      unsigned short u[8];
      u[0] = f2bf(wrr[r][0].x); u[1] = f2bf(wrr[r][0].y);
      u[2] = f2bf(wrr[r][0].z); u[3] = f2bf(wrr[r][0].w);
      u[4] = f2bf(wrr[r][1].x); u[5] = f2bf(wrr[r][1].y);
      u[6] = f2bf(wrr[r][1].z); u[7] = f2bf(wrr[r][1].w);
      *(uint4*)(Wsh + (srow + 32 * r) * 72 + soff) = *(uint4*)u;
    }
    if (kk < 7) {
      const int c0 = (kk + 1) * 64;
      orr = *(const uint4*)(Og + c0);
#pragma unroll
      for (int r = 0; r < 2; ++r) {
        wrr[r][0] = *(const float4*)(Wg + (size_t)(32 * r) * FF_ + c0);
        wrr[r][1] = *(const float4*)(Wg + (size_t)(32 * r) * FF_ + c0 + 4);
      }
    }
    __syncthreads();
    short8 aF[2][2], bF[2];
#pragma unroll
    for (int i = 0; i < 2; ++i) {
      aF[i][0] = *(const short8*)(Osh + (16 * i + lx) * 72 + q * 8);
      aF[i][1] = *(const short8*)(Osh + (16 * i + lx) * 72 + 32 + q * 8);
    }
    bF[0] = *(const short8*)(Wsh + (16 * w + lx) * 72 + q * 8);
    bF[1] = *(const short8*)(Wsh + (16 * w + lx) * 72 + 32 + q * 8);
#pragma unroll
    for (int i = 0; i < 2; ++i) {
      acc[i] = __builtin_amdgcn_mfma_f32_16x16x32_bf16(aF[i][0], bF[0], acc[i], 0, 0, 0);
      acc[i] = __builtin_amdgcn_mfma_f32_16x16x32_bf16(aF[i][1], bF[1], acc[i], 0, 0, 0);
    }
  }

  const int o = o0 + 16 * w + lx;
  const float bias = bo[o];
#pragma unroll
  for (int i = 0; i < 2; ++i) {
    const int n = n0 + 16 * i + 4 * q;
    const float4 xv = *(const float4*)(x + ((size_t)(b * CIN_ + o)) * NTOK_ + n);
    float4 v;
    v.x = fmaxf(acc[i][0] + bias, 0.f) + xv.x;
    v.y = fmaxf(acc[i][1] + bias, 0.f) + xv.y;
    v.z = fmaxf(acc[i][2] + bias, 0.f) + xv.z;
    v.w = fmaxf(acc[i][3] + bias, 0.f) + xv.w;
    *(float4*)(pre + ((size_t)(b * COUT_ + o)) * NTOK_ + n) = v;
  }
}

// ---------------------------------------------------------------------------
// Kernel 4 (R9): BatchNorm in place, 512 threads/block.
// ---------------------------------------------------------------------------
__global__ __launch_bounds__(512) void bn_kernel(
    float* __restrict__ out, const float* __restrict__ gamma,
    const float* __restrict__ beta) {
  __shared__ float red[16];
  const int c = blockIdx.x;
  const int tid = threadIdx.x;
  const int lane = tid & 63, w = tid >> 6;

  float4 v[2];
  float s = 0.f, s2 = 0.f;
#pragma unroll
  for (int b = 0; b < BB_; ++b) {
    float* base = out + ((size_t)(b * COUT_ + c)) * NTOK_;
    const float4 t = *(const float4*)(base + 4 * tid);
    v[b] = t;
    s += t.x + t.y + t.z + t.w;
    s2 += t.x * t.x + t.y * t.y + t.z * t.z + t.w * t.w;
  }
#pragma unroll
  for (int off = 32; off >= 1; off >>= 1) {
    s += __shfl_xor(s, off);
    s2 += __shfl_xor(s2, off);
  }
  if (lane == 0) { red[w] = s; red[8 + w] = s2; }
  __syncthreads();
  float S = 0.f, S2 = 0.f;
#pragma unroll
  for (int i = 0; i < 8; ++i) { S += red[i]; S2 += red[8 + i]; }
  const float inv = 1.0f / (float)(BB_ * NTOK_);
  const float mean = S * inv;
  const float var = S2 * inv - mean * mean;
  const float sc = rsqrtf(var + BNEPS_) * gamma[c];
  const float bt = beta[c];
#pragma unroll
  for (int b = 0; b < BB_; ++b) {
    float* base = out + ((size_t)(b * COUT_ + c)) * NTOK_;
    float4 t = v[b];
    t.x = (t.x - mean) * sc + bt;
    t.y = (t.y - mean) * sc + bt;
    t.z = (t.z - mean) * sc + bt;
    t.w = (t.w - mean) * sc + bt;
    *(float4*)(base + 4 * tid) = t;
  }
}

extern "C" void kernel_launch(void* const* d_in, const int* in_sizes, int n_in,
                              void* d_out, int out_size, void* d_ws, size_t ws_size,
                              hipStream_t stream) {
  (void)in_sizes; (void)n_in; (void)out_size; (void)ws_size;
  const float* x = (const float*)d_in[0];
  const float* WK = (const float*)d_in[1];
  const float* WQ = (const float*)d_in[2];
  const float* WV = (const float*)d_in[3];
  const float* Wo = (const float*)d_in[4];
  const float* bo = (const float*)d_in[5];
  const float* gamma = (const float*)d_in[6];
  const float* beta = (const float*)d_in[7];

  char* ws = (char*)d_ws;
  unsigned short* Kb  = (unsigned short*)(ws + 3145728);          // 4 MB
  unsigned short* Qb  = (unsigned short*)(ws + 7340032);          // 4 MB
  unsigned short* Vt  = (unsigned short*)(ws + 11534336);         // 4 MB
  unsigned short* Ob  = (unsigned short*)(ws + 15728640);         // 4 MB
  float* out = (float*)d_out;

  qkv_kernel<<<dim3(32, 4, 6), 256, 0, stream>>>(x, WK, WQ, WV, Kb, Qb, Vt);
  attn_kernel<<<dim3(512, 1, 1), 256, 0, stream>>>(Kb, Qb, Vt, Ob);
  proj_kernel<<<dim3(64, 4, 2), 256, 0, stream>>>(Ob, Wo, bo, x, out);
  bn_kernel<<<256, 512, 0, stream>>>(out, gamma, beta);
}